// Round 11
// baseline (247.161 us; speedup 1.0000x reference)
//
#include <hip/hip_runtime.h>
#include <hip/hip_bf16.h>
#include <stdint.h>

// Problem constants
#define M_TOK 16384   // B*S = 8*2048
#define E_DIM 768
#define FF_DIM 3072
#define Q_N 8

typedef __attribute__((ext_vector_type(8))) short bf16x8;
typedef __attribute__((ext_vector_type(4))) float f32x4;

__device__ inline unsigned short f2bf(float f) {
  union { float f; unsigned u; } v; v.f = f;
  unsigned r = v.u + 0x7fffu + ((v.u >> 16) & 1u);  // round-to-nearest-even
  return (unsigned short)(r >> 16);
}

// ---- prep kernel: blocks [0,512) compute h (16B stores); blocks [512,1088)
//      convert w2 -> bf16 (16 elems/thread). One launch replaces two.
//      h math is BIT-IDENTICAL to the verified compute_h: f32 cos in same
//      order, fmaf ascending q, fmaxf, f2bf, even-f-low packing.
#define H_BLOCKS 512
#define CVT_BLOCKS 576   // E*FF / (256*16) = 2359296/4096

__global__ __launch_bounds__(256) void prep_fused(const float* __restrict__ x,
                                                  const float* __restrict__ phi,
                                                  const float* __restrict__ w1,
                                                  const float* __restrict__ b1,
                                                  const float* __restrict__ w2,
                                                  __hip_bfloat16* __restrict__ hout,
                                                  __hip_bfloat16* __restrict__ w2b) {
  if (blockIdx.x >= H_BLOCKS) {
    // ---- w2 fp32 -> bf16, 16 elems/thread ----
    const int i0 = ((blockIdx.x - H_BLOCKS) * 256 + threadIdx.x) * 16;
    const float4* src = (const float4*)(w2 + i0);
    float4 v0 = src[0], v1 = src[1], v2 = src[2], v3 = src[3];
    uint4 o0, o1;
    o0.x = (uint32_t)f2bf(v0.x) | ((uint32_t)f2bf(v0.y) << 16);
    o0.y = (uint32_t)f2bf(v0.z) | ((uint32_t)f2bf(v0.w) << 16);
    o0.z = (uint32_t)f2bf(v1.x) | ((uint32_t)f2bf(v1.y) << 16);
    o0.w = (uint32_t)f2bf(v1.z) | ((uint32_t)f2bf(v1.w) << 16);
    o1.x = (uint32_t)f2bf(v2.x) | ((uint32_t)f2bf(v2.y) << 16);
    o1.y = (uint32_t)f2bf(v2.z) | ((uint32_t)f2bf(v2.w) << 16);
    o1.z = (uint32_t)f2bf(v3.x) | ((uint32_t)f2bf(v3.y) << 16);
    o1.w = (uint32_t)f2bf(v3.z) | ((uint32_t)f2bf(v3.w) << 16);
    uint4* dst = (uint4*)((unsigned short*)w2b + i0);
    dst[0] = o0;
    dst[1] = o1;
    return;
  }

  // ---- h = relu(cos(x[:, :8]+phi) @ w1^T + b1), bf16, 16B stores ----
  __shared__ float s_meas[32][8];
  const int t = threadIdx.x;
  const int m0 = blockIdx.x * 32;

  if (t < 64) {
    int m = t >> 1, hh = t & 1;
    float4 v = *(const float4*)(x + (size_t)(m0 + m) * E_DIM + hh * 4);
    float4 p = *(const float4*)(phi + hh * 4);
    s_meas[m][hh * 4 + 0] = __cosf(v.x + p.x);
    s_meas[m][hh * 4 + 1] = __cosf(v.y + p.y);
    s_meas[m][hh * 4 + 2] = __cosf(v.z + p.z);
    s_meas[m][hh * 4 + 3] = __cosf(v.w + p.w);
  }
  __syncthreads();

  const int mi = t >> 3;   // 0..31
  const int fc = t & 7;    // 0..7

  float mv[8];
  {
    f32x4 a = *(const f32x4*)&s_meas[mi][0];
    f32x4 b = *(const f32x4*)&s_meas[mi][4];
    mv[0] = a[0]; mv[1] = a[1]; mv[2] = a[2]; mv[3] = a[3];
    mv[4] = b[0]; mv[5] = b[1]; mv[6] = b[2]; mv[7] = b[3];
  }

  uint4* dst = (uint4*)((unsigned short*)hout + (size_t)(m0 + mi) * FF_DIM);
#pragma unroll 2
  for (int fg = fc; fg < FF_DIM / 8; fg += 8) {
    // 8 output features f = fg*8 .. fg*8+7; w1 rows are 8 floats each
    const float4* wr = (const float4*)(w1 + (size_t)fg * 8 * Q_N);
    const float4 b1lo = *(const float4*)(b1 + fg * 8);
    const float4 b1hi = *(const float4*)(b1 + fg * 8 + 4);
    uint32_t pk[4];
#pragma unroll
    for (int j = 0; j < 8; ++j) {
      float4 a0 = wr[j * 2];
      float4 a1 = wr[j * 2 + 1];
      float a;
      switch (j) {          // bias, same source as before: b1[f]
        case 0: a = b1lo.x; break;
        case 1: a = b1lo.y; break;
        case 2: a = b1lo.z; break;
        case 3: a = b1lo.w; break;
        case 4: a = b1hi.x; break;
        case 5: a = b1hi.y; break;
        case 6: a = b1hi.z; break;
        default: a = b1hi.w; break;
      }
      a = fmaf(mv[0], a0.x, a);
      a = fmaf(mv[1], a0.y, a);
      a = fmaf(mv[2], a0.z, a);
      a = fmaf(mv[3], a0.w, a);
      a = fmaf(mv[4], a1.x, a);
      a = fmaf(mv[5], a1.y, a);
      a = fmaf(mv[6], a1.z, a);
      a = fmaf(mv[7], a1.w, a);
      a = fmaxf(a, 0.f);
      unsigned short u = f2bf(a);
      if (j & 1) pk[j >> 1] |= ((uint32_t)u) << 16;
      else pk[j >> 1] = (uint32_t)u;
    }
    uint4 pv; pv.x = pk[0]; pv.y = pk[1]; pv.z = pk[2]; pv.w = pk[3];
    dst[fg] = pv;
  }
}

// ---------------- kernel 2: C[M,N] = h[M,K] @ w2b[N,K]^T + b2 ---------------
// R11: GEMM reverted to the best-measured variant (R5, total 98.4us):
// BM=256, BN=192, BK=64, grid 64x4=256; 512 thr, waves 4Mx2N -> wave tile
// 64x96, acc[4][6]; stage-at-top, k-half frag scopes, setprio, vmcnt(0),
// one barrier per tile. Eight structural variants (phase-split, counted
// vmcnt, 2-blk occupancy, wave shapes, triple-buffer, 256^2, B-direct)
// all measured 71-88us -> this 2-barrier body is the empirical floor of
// the family; remaining session effort goes to the prep stage.
#define GLDS16(g, l)                                                          \
  __builtin_amdgcn_global_load_lds(                                           \
      (const __attribute__((address_space(1))) void*)(g),                     \
      (__attribute__((address_space(3))) void*)(l), 16, 0, 0)

#define BUF_ELEMS 28672   // (256*64 + 192*64) bf16 elems = 56KB
#define B_OFF 16384       // A region: 256*64 elems

__global__ __launch_bounds__(512, 1) void gemm_bt(const __hip_bfloat16* __restrict__ A,
                                                  const __hip_bfloat16* __restrict__ Bw,
                                                  const float* __restrict__ b2,
                                                  float* __restrict__ C) {
  const int K = FF_DIM;   // 3072
  const int N = E_DIM;    // 768

  __shared__ __align__(16) __hip_bfloat16 lds[2 * BUF_ELEMS];  // 112 KiB

  const int t = threadIdx.x;
  // XCD-aware bijective swizzle: nwg = 256, 256 % 8 == 0
  const int swz = (blockIdx.x & 7) * 32 + (blockIdx.x >> 3);
  const int bm = swz >> 2;        // 0..63
  const int bn = swz & 3;         // 0..3
  const size_t m0 = (size_t)bm * 256;
  const int n0 = bn * 192;

  const int w = t >> 6, l = t & 63;
  const int wr = w >> 1;          // 0..3  (M wave row, 64 rows each)
  const int wc = w & 1;           // 0..1  (N wave col, 96 cols each)
  const int lr = l & 15;
  const int lk = l >> 4;          // 0..3

  // fragment-read swizzled chunk constants: row&7 == lr&7 for all frag rows
  const int x0 = lk ^ (lr & 7);        // k-half 0 chunk
  const int x1 = x0 ^ 4;               // k-half 1 chunk
  const int baseA = (wr * 64 + lr) * 64;
  const int baseB = B_OFF + (wc * 96 + lr) * 64;
  const int offA0 = baseA + x0 * 8, offA1 = baseA + x1 * 8;
  const int offB0 = baseB + x0 * 8, offB1 = baseB + x1 * 8;

  // staging: span = 64 rows x 128B = 8KB = 512 thr x 16B. dest = t*16B (linear).
  // row-in-span rs = t>>3, phys chunk pc = t&7, logical chunk lc = pc ^ (rs&7).
  const int rs = t >> 3;
  const int lc = (t & 7) ^ (rs & 7);
  const __hip_bfloat16* sA[4];
  const __hip_bfloat16* sB[3];
#pragma unroll
  for (int s = 0; s < 4; ++s) sA[s] = A + (m0 + s * 64 + rs) * (size_t)K + lc * 8;
#pragma unroll
  for (int s = 0; s < 3; ++s) sB[s] = Bw + ((size_t)n0 + s * 64 + rs) * K + lc * 8;

  f32x4 acc[4][6] = {};

#define STAGE(K0S, WBUF)                                                      \
  {                                                                           \
    __hip_bfloat16* ld = lds + (WBUF) * BUF_ELEMS + t * 8;                    \
    GLDS16(sA[0] + (K0S), ld);                                                \
    GLDS16(sA[1] + (K0S), ld + 4096);                                         \
    GLDS16(sA[2] + (K0S), ld + 8192);                                         \
    GLDS16(sA[3] + (K0S), ld + 12288);                                        \
    GLDS16(sB[0] + (K0S), ld + 16384);                                        \
    GLDS16(sB[1] + (K0S), ld + 20480);                                        \
    GLDS16(sB[2] + (K0S), ld + 24576);                                        \
  }

#define TILE(KT, RBUF, DO_STAGE)                                              \
  {                                                                           \
    if (DO_STAGE) STAGE(((KT) + 1) * 64, (RBUF) ^ 1);                         \
    const __hip_bfloat16* la = lds + (RBUF) * BUF_ELEMS;                      \
    { /* ---- k-half 0 ---- */                                                \
      bf16x8 fa[4], fb[6];                                                    \
      _Pragma("unroll") for (int mi = 0; mi < 4; ++mi)                        \
          fa[mi] = *(const bf16x8*)(la + offA0 + mi * 1024);                  \
      _Pragma("unroll") for (int ni = 0; ni < 6; ++ni)                        \
          fb[ni] = *(const bf16x8*)(la + offB0 + ni * 1024);                  \
      __builtin_amdgcn_s_setprio(1);                                          \
      _Pragma("unroll") for (int mi = 0; mi < 4; ++mi)                        \
          _Pragma("unroll") for (int ni = 0; ni < 6; ++ni)                    \
              acc[mi][ni] = __builtin_amdgcn_mfma_f32_16x16x32_bf16(          \
                  fa[mi], fb[ni], acc[mi][ni], 0, 0, 0);                      \
      __builtin_amdgcn_s_setprio(0);                                          \
    }                                                                         \
    { /* ---- k-half 1 ---- */                                                \
      bf16x8 fa[4], fb[6];                                                    \
      _Pragma("unroll") for (int mi = 0; mi < 4; ++mi)                        \
          fa[mi] = *(const bf16x8*)(la + offA1 + mi * 1024);                  \
      _Pragma("unroll") for (int ni = 0; ni < 6; ++ni)                        \
          fb[ni] = *(const bf16x8*)(la + offB1 + ni * 1024);                  \
      __builtin_amdgcn_s_setprio(1);                                          \
      _Pragma("unroll") for (int mi = 0; mi < 4; ++mi)                        \
          _Pragma("unroll") for (int ni = 0; ni < 6; ++ni)                    \
              acc[mi][ni] = __builtin_amdgcn_mfma_f32_16x16x32_bf16(          \
                  fa[mi], fb[ni], acc[mi][ni], 0, 0, 0);                      \
      __builtin_amdgcn_s_setprio(0);                                          \
    }                                                                         \
    asm volatile("s_waitcnt vmcnt(0)" ::: "memory");                          \
    __builtin_amdgcn_s_barrier();                                             \
  }

  // prologue: stage tile 0 into buf 0
  STAGE(0, 0);
  asm volatile("s_waitcnt vmcnt(0)" ::: "memory");
  __builtin_amdgcn_s_barrier();

  // main: 48 K-tiles of 64, two per iteration (static buffers)
#pragma unroll 1
  for (int tt = 0; tt < 46; tt += 2) {
    TILE(tt + 0, 0, 1);
    TILE(tt + 1, 1, 1);
  }
  TILE(46, 0, 1);
  TILE(47, 1, 0);

#undef TILE
#undef STAGE

  // epilogue: C/D layout col = l&15, row = (l>>4)*4 + r
#pragma unroll
  for (int mi = 0; mi < 4; ++mi) {
    const size_t row = m0 + wr * 64 + mi * 16 + lk * 4;
#pragma unroll
    for (int ni = 0; ni < 6; ++ni) {
      const int col = n0 + wc * 96 + ni * 16 + lr;
      const float bias = b2[col];
#pragma unroll
      for (int rr = 0; rr < 4; ++rr) {
        C[(row + rr) * N + col] = acc[mi][ni][rr] + bias;
      }
    }
  }
}

// ---------------- fallback: correct fp32 path if workspace too small --------
__global__ __launch_bounds__(256) void fallback_fused(const float* __restrict__ x,
                                                      const float* __restrict__ phi,
                                                      const float* __restrict__ w1,
                                                      const float* __restrict__ b1,
                                                      const float* __restrict__ w2,
                                                      const float* __restrict__ b2,
                                                      float* __restrict__ out) {
  __shared__ float s_h[FF_DIM];
  __shared__ float s_meas[Q_N];
  const int t = threadIdx.x;
  const size_t m = blockIdx.x;
  if (t < Q_N) s_meas[t] = __cosf(x[m * E_DIM + t] + phi[t]);
  __syncthreads();
  for (int f = t; f < FF_DIM; f += 256) {
    const float4* wr = (const float4*)(w1 + (size_t)f * Q_N);
    float4 a = wr[0], b = wr[1];
    float acc = b1[f];
    acc = fmaf(s_meas[0], a.x, acc); acc = fmaf(s_meas[1], a.y, acc);
    acc = fmaf(s_meas[2], a.z, acc); acc = fmaf(s_meas[3], a.w, acc);
    acc = fmaf(s_meas[4], b.x, acc); acc = fmaf(s_meas[5], b.y, acc);
    acc = fmaf(s_meas[6], b.z, acc); acc = fmaf(s_meas[7], b.w, acc);
    s_h[f] = fmaxf(acc, 0.f);
  }
  __syncthreads();
  for (int e = t; e < E_DIM; e += 256) {
    const float* w2r = w2 + (size_t)e * FF_DIM;
    float acc = b2[e];
    for (int f = 0; f < FF_DIM; f += 4) {
      float4 wv = *(const float4*)(w2r + f);
      acc = fmaf(s_h[f + 0], wv.x, acc);
      acc = fmaf(s_h[f + 1], wv.y, acc);
      acc = fmaf(s_h[f + 2], wv.z, acc);
      acc = fmaf(s_h[f + 3], wv.w, acc);
    }
    out[m * E_DIM + e] = acc;
  }
}

extern "C" void kernel_launch(void* const* d_in, const int* in_sizes, int n_in,
                              void* d_out, int out_size, void* d_ws, size_t ws_size,
                              hipStream_t stream) {
  const float* x   = (const float*)d_in[0];
  const float* phi = (const float*)d_in[1];
  const float* w1  = (const float*)d_in[2];
  const float* b1  = (const float*)d_in[3];
  const float* w2  = (const float*)d_in[4];
  const float* b2  = (const float*)d_in[5];
  float* out = (float*)d_out;

  const size_t H_BYTES   = (size_t)M_TOK * FF_DIM * 2;   // 100,663,296
  const size_t W2B_BYTES = (size_t)E_DIM * FF_DIM * 2;   // 4,718,592
  const size_t NEED = H_BYTES + W2B_BYTES;

  if (ws_size >= NEED) {
    __hip_bfloat16* h   = (__hip_bfloat16*)d_ws;
    __hip_bfloat16* w2b = (__hip_bfloat16*)((char*)d_ws + H_BYTES);
    // one launch: h production (512 blocks) + w2 conversion (576 blocks)
    prep_fused<<<H_BLOCKS + CVT_BLOCKS, 256, 0, stream>>>(x, phi, w1, b1, w2,
                                                          h, w2b);
    // BM=256, BN=192 -> 64*4 = 256 workgroups (matches in-kernel swizzle)
    gemm_bt<<<(M_TOK / 256) * (E_DIM / 192), 512, 0, stream>>>(h, w2b, b2, out);
  } else {
    fallback_fused<<<M_TOK, 256, 0, stream>>>(x, phi, w1, b1, w2, b2, out);
  }
}

// Round 12
// 95.551 us; speedup vs baseline: 2.5867x; 2.5867x over previous
//
#include <hip/hip_runtime.h>
#include <hip/hip_bf16.h>
#include <stdint.h>

// Problem constants
#define M_TOK 16384   // B*S = 8*2048
#define E_DIM 768
#define FF_DIM 3072
#define Q_N 8

typedef __attribute__((ext_vector_type(8))) short bf16x8;
typedef __attribute__((ext_vector_type(4))) float f32x4;

__device__ inline unsigned short f2bf(float f) {
  union { float f; unsigned u; } v; v.f = f;
  unsigned r = v.u + 0x7fffu + ((v.u >> 16) & 1u);  // round-to-nearest-even
  return (unsigned short)(r >> 16);
}

// ---- prep kernel ----------------------------------------------------------
// Blocks [0, H_BLOCKS): h = relu(cos(x[:, :8]+phi) @ w1^T + b1) -> bf16.
//   R12: PROVEN compute_h structure (w1 slice in registers ONCE, loop over
//   32 m-rows — R11's inversion destroyed this reuse and died at 187us),
//   widened 2 -> 4 features/thread: w1 regs 64B->128B, stores 4B -> 8B
//   (uint2; per-wave 512B contiguous). Math bit-identical: f32 cos in same
//   order, fmaf ascending q, fmaxf, f2bf, even-feature-low packing.
// Blocks [H_BLOCKS, H_BLOCKS+CVT_BLOCKS): w2 fp32 -> bf16 (16 elems/thread,
//   verified in R11 — the cvt path was correct; only the h path regressed).
#define H_BLOCKS 1536    // (M_TOK/32) * (FF_DIM/1024)
#define CVT_BLOCKS 576   // E*FF / (256*16)

__global__ __launch_bounds__(256) void prep_fused(const float* __restrict__ x,
                                                  const float* __restrict__ phi,
                                                  const float* __restrict__ w1,
                                                  const float* __restrict__ b1,
                                                  const float* __restrict__ w2,
                                                  __hip_bfloat16* __restrict__ hout,
                                                  __hip_bfloat16* __restrict__ w2b) {
  if (blockIdx.x >= H_BLOCKS) {
    // ---- w2 fp32 -> bf16, 16 elems/thread ----
    const int i0 = ((blockIdx.x - H_BLOCKS) * 256 + threadIdx.x) * 16;
    const float4* src = (const float4*)(w2 + i0);
    float4 v0 = src[0], v1 = src[1], v2 = src[2], v3 = src[3];
    uint4 o0, o1;
    o0.x = (uint32_t)f2bf(v0.x) | ((uint32_t)f2bf(v0.y) << 16);
    o0.y = (uint32_t)f2bf(v0.z) | ((uint32_t)f2bf(v0.w) << 16);
    o0.z = (uint32_t)f2bf(v1.x) | ((uint32_t)f2bf(v1.y) << 16);
    o0.w = (uint32_t)f2bf(v1.z) | ((uint32_t)f2bf(v1.w) << 16);
    o1.x = (uint32_t)f2bf(v2.x) | ((uint32_t)f2bf(v2.y) << 16);
    o1.y = (uint32_t)f2bf(v2.z) | ((uint32_t)f2bf(v2.w) << 16);
    o1.z = (uint32_t)f2bf(v3.x) | ((uint32_t)f2bf(v3.y) << 16);
    o1.w = (uint32_t)f2bf(v3.z) | ((uint32_t)f2bf(v3.w) << 16);
    uint4* dst = (uint4*)((unsigned short*)w2b + i0);
    dst[0] = o0;
    dst[1] = o1;
    return;
  }

  // ---- h path ----
  __shared__ float s_meas[32][8];
  const int t = threadIdx.x;
  const int bm = blockIdx.x / 3;       // m-tile (32 rows)
  const int bf = blockIdx.x % 3;       // f-tile (1024 features)
  const int m0 = bm * 32;
  const int f0 = bf * 1024;

  if (t < 64) {
    int m = t >> 1, hh = t & 1;
    float4 v = *(const float4*)(x + (size_t)(m0 + m) * E_DIM + hh * 4);
    float4 p = *(const float4*)(phi + hh * 4);
    s_meas[m][hh * 4 + 0] = __cosf(v.x + p.x);
    s_meas[m][hh * 4 + 1] = __cosf(v.y + p.y);
    s_meas[m][hh * 4 + 2] = __cosf(v.z + p.z);
    s_meas[m][hh * 4 + 3] = __cosf(v.w + p.w);
  }
  __syncthreads();

  // this thread owns features f = f0 + 4t .. f0 + 4t + 3
  const float4* wrp = (const float4*)(w1 + (size_t)(f0 + 4 * t) * Q_N);
  float4 wv[8];
#pragma unroll
  for (int j = 0; j < 8; ++j) wv[j] = wrp[j];        // 128 B, resident once
  const float4 bias4 = *(const float4*)(b1 + f0 + 4 * t);

  unsigned short* hbase = (unsigned short*)hout + f0 + 4 * t;
  for (int m = 0; m < 32; ++m) {
    float mvv[8];
#pragma unroll
    for (int q = 0; q < 8; ++q) mvv[q] = s_meas[m][q];
    float a0 = bias4.x, a1 = bias4.y, a2 = bias4.z, a3 = bias4.w;
    // ascending-q fmaf chains, identical order to the verified compute_h
    a0 = fmaf(mvv[0], wv[0].x, a0); a0 = fmaf(mvv[1], wv[0].y, a0);
    a0 = fmaf(mvv[2], wv[0].z, a0); a0 = fmaf(mvv[3], wv[0].w, a0);
    a0 = fmaf(mvv[4], wv[1].x, a0); a0 = fmaf(mvv[5], wv[1].y, a0);
    a0 = fmaf(mvv[6], wv[1].z, a0); a0 = fmaf(mvv[7], wv[1].w, a0);
    a1 = fmaf(mvv[0], wv[2].x, a1); a1 = fmaf(mvv[1], wv[2].y, a1);
    a1 = fmaf(mvv[2], wv[2].z, a1); a1 = fmaf(mvv[3], wv[2].w, a1);
    a1 = fmaf(mvv[4], wv[3].x, a1); a1 = fmaf(mvv[5], wv[3].y, a1);
    a1 = fmaf(mvv[6], wv[3].z, a1); a1 = fmaf(mvv[7], wv[3].w, a1);
    a2 = fmaf(mvv[0], wv[4].x, a2); a2 = fmaf(mvv[1], wv[4].y, a2);
    a2 = fmaf(mvv[2], wv[4].z, a2); a2 = fmaf(mvv[3], wv[4].w, a2);
    a2 = fmaf(mvv[4], wv[5].x, a2); a2 = fmaf(mvv[5], wv[5].y, a2);
    a2 = fmaf(mvv[6], wv[5].z, a2); a2 = fmaf(mvv[7], wv[5].w, a2);
    a3 = fmaf(mvv[0], wv[6].x, a3); a3 = fmaf(mvv[1], wv[6].y, a3);
    a3 = fmaf(mvv[2], wv[6].z, a3); a3 = fmaf(mvv[3], wv[6].w, a3);
    a3 = fmaf(mvv[4], wv[7].x, a3); a3 = fmaf(mvv[5], wv[7].y, a3);
    a3 = fmaf(mvv[6], wv[7].z, a3); a3 = fmaf(mvv[7], wv[7].w, a3);
    a0 = fmaxf(a0, 0.f); a1 = fmaxf(a1, 0.f);
    a2 = fmaxf(a2, 0.f); a3 = fmaxf(a3, 0.f);
    uint2 pv;
    pv.x = (uint32_t)f2bf(a0) | ((uint32_t)f2bf(a1) << 16);
    pv.y = (uint32_t)f2bf(a2) | ((uint32_t)f2bf(a3) << 16);
    *(uint2*)(hbase + (size_t)(m0 + m) * FF_DIM) = pv;
  }
}

// ---------------- kernel 2: C[M,N] = h[M,K] @ w2b[N,K]^T + b2 ---------------
// GEMM: best-measured variant (R5 family, total 98.4us). BM=256, BN=192,
// BK=64, grid 64x4=256; 512 thr, waves 4Mx2N -> wave tile 64x96, acc[4][6];
// stage-at-top, k-half frag scopes, setprio, vmcnt(0), 1 barrier/tile.
// Nine structural variants (phase-split, counted vmcnt, 2-blk occupancy,
// wave shapes, triple-buffer, 256^2, B-direct, fusion x2) measured 71-146us
// -> this body is the empirical floor of the family; left untouched.
#define GLDS16(g, l)                                                          \
  __builtin_amdgcn_global_load_lds(                                           \
      (const __attribute__((address_space(1))) void*)(g),                     \
      (__attribute__((address_space(3))) void*)(l), 16, 0, 0)

#define BUF_ELEMS 28672   // (256*64 + 192*64) bf16 elems = 56KB
#define B_OFF 16384       // A region: 256*64 elems

__global__ __launch_bounds__(512, 1) void gemm_bt(const __hip_bfloat16* __restrict__ A,
                                                  const __hip_bfloat16* __restrict__ Bw,
                                                  const float* __restrict__ b2,
                                                  float* __restrict__ C) {
  const int K = FF_DIM;   // 3072
  const int N = E_DIM;    // 768

  __shared__ __align__(16) __hip_bfloat16 lds[2 * BUF_ELEMS];  // 112 KiB

  const int t = threadIdx.x;
  // XCD-aware bijective swizzle: nwg = 256, 256 % 8 == 0
  const int swz = (blockIdx.x & 7) * 32 + (blockIdx.x >> 3);
  const int bm = swz >> 2;        // 0..63
  const int bn = swz & 3;         // 0..3
  const size_t m0 = (size_t)bm * 256;
  const int n0 = bn * 192;

  const int w = t >> 6, l = t & 63;
  const int wr = w >> 1;          // 0..3  (M wave row, 64 rows each)
  const int wc = w & 1;           // 0..1  (N wave col, 96 cols each)
  const int lr = l & 15;
  const int lk = l >> 4;          // 0..3

  // fragment-read swizzled chunk constants: row&7 == lr&7 for all frag rows
  const int x0 = lk ^ (lr & 7);        // k-half 0 chunk
  const int x1 = x0 ^ 4;               // k-half 1 chunk
  const int baseA = (wr * 64 + lr) * 64;
  const int baseB = B_OFF + (wc * 96 + lr) * 64;
  const int offA0 = baseA + x0 * 8, offA1 = baseA + x1 * 8;
  const int offB0 = baseB + x0 * 8, offB1 = baseB + x1 * 8;

  // staging: span = 64 rows x 128B = 8KB = 512 thr x 16B. dest = t*16B (linear).
  // row-in-span rs = t>>3, phys chunk pc = t&7, logical chunk lc = pc ^ (rs&7).
  const int rs = t >> 3;
  const int lc = (t & 7) ^ (rs & 7);
  const __hip_bfloat16* sA[4];
  const __hip_bfloat16* sB[3];
#pragma unroll
  for (int s = 0; s < 4; ++s) sA[s] = A + (m0 + s * 64 + rs) * (size_t)K + lc * 8;
#pragma unroll
  for (int s = 0; s < 3; ++s) sB[s] = Bw + ((size_t)n0 + s * 64 + rs) * K + lc * 8;

  f32x4 acc[4][6] = {};

#define STAGE(K0S, WBUF)                                                      \
  {                                                                           \
    __hip_bfloat16* ld = lds + (WBUF) * BUF_ELEMS + t * 8;                    \
    GLDS16(sA[0] + (K0S), ld);                                                \
    GLDS16(sA[1] + (K0S), ld + 4096);                                         \
    GLDS16(sA[2] + (K0S), ld + 8192);                                         \
    GLDS16(sA[3] + (K0S), ld + 12288);                                        \
    GLDS16(sB[0] + (K0S), ld + 16384);                                        \
    GLDS16(sB[1] + (K0S), ld + 20480);                                        \
    GLDS16(sB[2] + (K0S), ld + 24576);                                        \
  }

#define TILE(KT, RBUF, DO_STAGE)                                              \
  {                                                                           \
    if (DO_STAGE) STAGE(((KT) + 1) * 64, (RBUF) ^ 1);                         \
    const __hip_bfloat16* la = lds + (RBUF) * BUF_ELEMS;                      \
    { /* ---- k-half 0 ---- */                                                \
      bf16x8 fa[4], fb[6];                                                    \
      _Pragma("unroll") for (int mi = 0; mi < 4; ++mi)                        \
          fa[mi] = *(const bf16x8*)(la + offA0 + mi * 1024);                  \
      _Pragma("unroll") for (int ni = 0; ni < 6; ++ni)                        \
          fb[ni] = *(const bf16x8*)(la + offB0 + ni * 1024);                  \
      __builtin_amdgcn_s_setprio(1);                                          \
      _Pragma("unroll") for (int mi = 0; mi < 4; ++mi)                        \
          _Pragma("unroll") for (int ni = 0; ni < 6; ++ni)                    \
              acc[mi][ni] = __builtin_amdgcn_mfma_f32_16x16x32_bf16(          \
                  fa[mi], fb[ni], acc[mi][ni], 0, 0, 0);                      \
      __builtin_amdgcn_s_setprio(0);                                          \
    }                                                                         \
    { /* ---- k-half 1 ---- */                                                \
      bf16x8 fa[4], fb[6];                                                    \
      _Pragma("unroll") for (int mi = 0; mi < 4; ++mi)                        \
          fa[mi] = *(const bf16x8*)(la + offA1 + mi * 1024);                  \
      _Pragma("unroll") for (int ni = 0; ni < 6; ++ni)                        \
          fb[ni] = *(const bf16x8*)(la + offB1 + ni * 1024);                  \
      __builtin_amdgcn_s_setprio(1);                                          \
      _Pragma("unroll") for (int mi = 0; mi < 4; ++mi)                        \
          _Pragma("unroll") for (int ni = 0; ni < 6; ++ni)                    \
              acc[mi][ni] = __builtin_amdgcn_mfma_f32_16x16x32_bf16(          \
                  fa[mi], fb[ni], acc[mi][ni], 0, 0, 0);                      \
      __builtin_amdgcn_s_setprio(0);                                          \
    }                                                                         \
    asm volatile("s_waitcnt vmcnt(0)" ::: "memory");                          \
    __builtin_amdgcn_s_barrier();                                             \
  }

  // prologue: stage tile 0 into buf 0
  STAGE(0, 0);
  asm volatile("s_waitcnt vmcnt(0)" ::: "memory");
  __builtin_amdgcn_s_barrier();

  // main: 48 K-tiles of 64, two per iteration (static buffers)
#pragma unroll 1
  for (int tt = 0; tt < 46; tt += 2) {
    TILE(tt + 0, 0, 1);
    TILE(tt + 1, 1, 1);
  }
  TILE(46, 0, 1);
  TILE(47, 1, 0);

#undef TILE
#undef STAGE

  // epilogue: C/D layout col = l&15, row = (l>>4)*4 + r
#pragma unroll
  for (int mi = 0; mi < 4; ++mi) {
    const size_t row = m0 + wr * 64 + mi * 16 + lk * 4;
#pragma unroll
    for (int ni = 0; ni < 6; ++ni) {
      const int col = n0 + wc * 96 + ni * 16 + lr;
      const float bias = b2[col];
#pragma unroll
      for (int rr = 0; rr < 4; ++rr) {
        C[(row + rr) * N + col] = acc[mi][ni][rr] + bias;
      }
    }
  }
}

// ---------------- fallback: correct fp32 path if workspace too small --------
__global__ __launch_bounds__(256) void fallback_fused(const float* __restrict__ x,
                                                      const float* __restrict__ phi,
                                                      const float* __restrict__ w1,
                                                      const float* __restrict__ b1,
                                                      const float* __restrict__ w2,
                                                      const float* __restrict__ b2,
                                                      float* __restrict__ out) {
  __shared__ float s_h[FF_DIM];
  __shared__ float s_meas[Q_N];
  const int t = threadIdx.x;
  const size_t m = blockIdx.x;
  if (t < Q_N) s_meas[t] = __cosf(x[m * E_DIM + t] + phi[t]);
  __syncthreads();
  for (int f = t; f < FF_DIM; f += 256) {
    const float4* wr = (const float4*)(w1 + (size_t)f * Q_N);
    float4 a = wr[0], b = wr[1];
    float acc = b1[f];
    acc = fmaf(s_meas[0], a.x, acc); acc = fmaf(s_meas[1], a.y, acc);
    acc = fmaf(s_meas[2], a.z, acc); acc = fmaf(s_meas[3], a.w, acc);
    acc = fmaf(s_meas[4], b.x, acc); acc = fmaf(s_meas[5], b.y, acc);
    acc = fmaf(s_meas[6], b.z, acc); acc = fmaf(s_meas[7], b.w, acc);
    s_h[f] = fmaxf(acc, 0.f);
  }
  __syncthreads();
  for (int e = t; e < E_DIM; e += 256) {
    const float* w2r = w2 + (size_t)e * FF_DIM;
    float acc = b2[e];
    for (int f = 0; f < FF_DIM; f += 4) {
      float4 wv = *(const float4*)(w2r + f);
      acc = fmaf(s_h[f + 0], wv.x, acc);
      acc = fmaf(s_h[f + 1], wv.y, acc);
      acc = fmaf(s_h[f + 2], wv.z, acc);
      acc = fmaf(s_h[f + 3], wv.w, acc);
    }
    out[m * E_DIM + e] = acc;
  }
}

extern "C" void kernel_launch(void* const* d_in, const int* in_sizes, int n_in,
                              void* d_out, int out_size, void* d_ws, size_t ws_size,
                              hipStream_t stream) {
  const float* x   = (const float*)d_in[0];
  const float* phi = (const float*)d_in[1];
  const float* w1  = (const float*)d_in[2];
  const float* b1  = (const float*)d_in[3];
  const float* w2  = (const float*)d_in[4];
  const float* b2  = (const float*)d_in[5];
  float* out = (float*)d_out;

  const size_t H_BYTES   = (size_t)M_TOK * FF_DIM * 2;   // 100,663,296
  const size_t W2B_BYTES = (size_t)E_DIM * FF_DIM * 2;   // 4,718,592
  const size_t NEED = H_BYTES + W2B_BYTES;

  if (ws_size >= NEED) {
    __hip_bfloat16* h   = (__hip_bfloat16*)d_ws;
    __hip_bfloat16* w2b = (__hip_bfloat16*)((char*)d_ws + H_BYTES);
    // one launch: h production (1536 blocks) + w2 conversion (576 blocks)
    prep_fused<<<H_BLOCKS + CVT_BLOCKS, 256, 0, stream>>>(x, phi, w1, b1, w2,
                                                          h, w2b);
    // BM=256, BN=192 -> 64*4 = 256 workgroups (matches in-kernel swizzle)
    gemm_bt<<<(M_TOK / 256) * (E_DIM / 192), 512, 0, stream>>>(h, w2b, b2, out);
  } else {
    fallback_fused<<<M_TOK, 256, 0, stream>>>(x, phi, w1, b1, w2, b2, out);
  }
}